// Round 7
// baseline (464.776 us; speedup 1.0000x reference)
//
#include <hip/hip_runtime.h>

#define NB_HG 2048   // H*G = 32*64
#define DIM_N 128
#define DIM_D 128
#define PH_ROWS 64   // d-rows per staging phase (32 KB LDS -> 4-5 blocks/CU)

// Numerics: per output element, strictly sequential ascending-d fp32 FMA
// (bit-matches harness golden; verified absmax=0 rounds 4-6). The d-loop is
// split into two staged phases; per-acc chain order is unchanged.
// LDS layout: Xt[dl][n ^ 4*(dl&7)] float4-XOR swizzle, conflict-free both
// ways (verified: SQ_LDS_BANK_CONFLICT = 0 in rounds 5-6).
__global__ __launch_bounds__(256, 4)
void qjl_sketch_kernel(const float* __restrict__ data,
                       const float* __restrict__ mask,
                       const float* __restrict__ proj,
                       int* __restrict__ out)
{
    __shared__ float Xt[PH_ROWS * DIM_N];  // 32 KB

    const int type = blockIdx.x;   // 0: inlier s<128, 1: inlier s>=128, 2: outlier s<128
    const int hg   = blockIdx.y;
    const int tid  = threadIdx.x;

    const int tn = tid & 15;                       // 16 n-groups
    const int ts = tid >> 4;                       // 16 s-groups
    const int C0 = 4 * tn;                         // first chunk base (floats)
    const int s0 = ((type == 1) ? 128 : 0) + ts * 8;
    const float* pbase = proj + (size_t)s0 * DIM_D;

    float acc[8][8];                               // [j: s-bit][i: n-slot]
    #pragma unroll
    for (int j = 0; j < 8; ++j)
        #pragma unroll
        for (int i = 0; i < 8; ++i) acc[j][i] = 0.0f;

    // staging indices (constant across phases)
    const int dl = tid & 63;                       // local LDS row
    const int nh = tid >> 6;                       // 0..3: n-quad within 16
    const int pcs = 4 * (dl & 7);                  // swizzle (== 4*(d&7), 64 | phase base)
    float* srow = &Xt[dl * DIM_N];

    #pragma unroll 1
    for (int p = 0; p < 2; ++p) {
        // ---------- stage masked, transposed, swizzled 64 d-rows ----------
        {
            const int   dg = p * PH_ROWS + dl;     // global d
            const float m  = mask[hg * DIM_D + dg];          // exactly 0.0f or 1.0f
            const float w  = (type == 2) ? m : (1.0f - m);
            const float* Xs = data + (size_t)hg * (DIM_N * DIM_D) + dg;
            #pragma unroll
            for (int g = 0; g < 8; ++g) {
                const int n0 = g * 16 + nh * 4;    // 4-aligned logical n block
                float4 v;
                v.x = Xs[(size_t)(n0 + 0) * DIM_D] * w;      // exact: w in {0,1}
                v.y = Xs[(size_t)(n0 + 1) * DIM_D] * w;
                v.z = Xs[(size_t)(n0 + 2) * DIM_D] * w;
                v.w = Xs[(size_t)(n0 + 3) * DIM_D] * w;
                *reinterpret_cast<float4*>(&srow[n0 ^ pcs]) = v;
            }
        }
        __syncthreads();

        // ---------- register-tiled masked GEMM over this phase's 64 d ----------
        const float* pb0 = pbase + p * PH_ROWS;
        for (int db = 0; db < PH_ROWS; db += 4) {
            // b-fragments: 8 projection rows, 4 consecutive d each (L1/L2-hot)
            float4 b[8];
            #pragma unroll
            for (int j = 0; j < 8; ++j)
                b[j] = *reinterpret_cast<const float4*>(pb0 + db + (size_t)j * DIM_D);

            #pragma unroll
            for (int dd = 0; dd < 4; ++dd) {       // ascending d within block
                const int d2 = db + dd;            // phase-local row
                const int P  = C0 ^ (4 * (d2 & 7));
                const float* r = &Xt[d2 * DIM_N + P];
                const float4 q0 = *reinterpret_cast<const float4*>(r);        // n=C0..+3
                const float4 q1 = *reinterpret_cast<const float4*>(r + 64);   // n=64+C0..

                #pragma unroll
                for (int j = 0; j < 8; ++j) {
                    const float bv = (dd == 0) ? b[j].x : (dd == 1) ? b[j].y
                                   : (dd == 2) ? b[j].z : b[j].w;
                    acc[j][0] = fmaf(bv, q0.x, acc[j][0]);   // serial dep: order fixed
                    acc[j][1] = fmaf(bv, q0.y, acc[j][1]);
                    acc[j][2] = fmaf(bv, q0.z, acc[j][2]);
                    acc[j][3] = fmaf(bv, q0.w, acc[j][3]);
                    acc[j][4] = fmaf(bv, q1.x, acc[j][4]);
                    acc[j][5] = fmaf(bv, q1.y, acc[j][5]);
                    acc[j][6] = fmaf(bv, q1.z, acc[j][6]);
                    acc[j][7] = fmaf(bv, q1.w, acc[j][7]);
                }
            }
        }
        if (p == 0) __syncthreads();               // all reads done before re-stage
    }

    // ---------- sign-pack (bit j = s0+j > 0) and store as int32 ----------
    const size_t inl_total = (size_t)NB_HG * DIM_N * 32;   // 8388608
    #pragma unroll
    for (int i = 0; i < 8; ++i) {
        int byte = 0;
        #pragma unroll
        for (int j = 0; j < 8; ++j)
            if (acc[j][i] > 0.0f) byte |= (1 << j);
        const int n = (i < 4) ? (C0 + i) : (64 + C0 + (i - 4));
        size_t idx;
        if (type == 2)
            idx = inl_total + ((size_t)hg * DIM_N + n) * 16 + ts;
        else
            idx = ((size_t)hg * DIM_N + n) * 32 + (type == 1 ? 16 : 0) + ts;
        out[idx] = byte;
    }
}

extern "C" void kernel_launch(void* const* d_in, const int* in_sizes, int n_in,
                              void* d_out, int out_size, void* d_ws, size_t ws_size,
                              hipStream_t stream) {
    const float* data = (const float*)d_in[0];   // (1,32,64,128,128) fp32
    const float* mask = (const float*)d_in[1];   // (1,32,64,128) fp32, values {0,1}
    const float* proj = (const float*)d_in[2];   // (256,128) fp32
    int* out = (int*)d_out;                      // 8388608 inlier + 4194304 outlier int32

    dim3 grid(3, NB_HG);
    qjl_sketch_kernel<<<grid, 256, 0, stream>>>(data, mask, proj, out);
}

// Round 8
// 367.339 us; speedup vs baseline: 1.2653x; 1.2653x over previous
//
#include <hip/hip_runtime.h>

#define NB_HG 2048   // H*G = 32*64
#define DIM_N 128
#define DIM_D 128
#define PH_ROWS 64   // d-rows per staging phase (32 KB LDS -> 4-5 blocks/CU)

// Numerics: per output element, strictly sequential ascending-d fp32 FMA
// (bit-matches harness golden; verified absmax=0 rounds 4-7). The d-loop is
// split into two staged phases; per-acc chain order is unchanged.
// LDS layout: Xt[dl][n ^ 4*(dl&7)] float4-XOR swizzle, conflict-free both
// ways (verified: SQ_LDS_BANK_CONFLICT = 0 in rounds 5-7).
// NOTE: no min-waves in launch_bounds — R7's (256,4) forced VGPR=64 and
// spilled acc[8][8] to scratch (WRITE_SIZE 49->218 MB). Occupancy comes from
// the 32 KB LDS tile + natural ~92-VGPR allocation instead.
__global__ __launch_bounds__(256)
void qjl_sketch_kernel(const float* __restrict__ data,
                       const float* __restrict__ mask,
                       const float* __restrict__ proj,
                       int* __restrict__ out)
{
    __shared__ float Xt[PH_ROWS * DIM_N];  // 32 KB

    const int type = blockIdx.x;   // 0: inlier s<128, 1: inlier s>=128, 2: outlier s<128
    const int hg   = blockIdx.y;
    const int tid  = threadIdx.x;

    const int tn = tid & 15;                       // 16 n-groups
    const int ts = tid >> 4;                       // 16 s-groups
    const int C0 = 4 * tn;                         // first chunk base (floats)
    const int s0 = ((type == 1) ? 128 : 0) + ts * 8;
    const float* pbase = proj + (size_t)s0 * DIM_D;

    float acc[8][8];                               // [j: s-bit][i: n-slot]
    #pragma unroll
    for (int j = 0; j < 8; ++j)
        #pragma unroll
        for (int i = 0; i < 8; ++i) acc[j][i] = 0.0f;

    // staging indices (constant across phases)
    const int dl = tid & 63;                       // local LDS row
    const int nh = tid >> 6;                       // 0..3: n-quad within 16
    const int pcs = 4 * (dl & 7);                  // swizzle (== 4*(d&7): 64 | phase base)
    float* srow = &Xt[dl * DIM_N];

    #pragma unroll 1
    for (int p = 0; p < 2; ++p) {
        // ---------- stage masked, transposed, swizzled 64 d-rows ----------
        {
            const int   dg = p * PH_ROWS + dl;     // global d
            const float m  = mask[hg * DIM_D + dg];          // exactly 0.0f or 1.0f
            const float w  = (type == 2) ? m : (1.0f - m);
            const float* Xs = data + (size_t)hg * (DIM_N * DIM_D) + dg;
            #pragma unroll
            for (int g = 0; g < 8; ++g) {
                const int n0 = g * 16 + nh * 4;    // 4-aligned logical n block
                float4 v;
                v.x = Xs[(size_t)(n0 + 0) * DIM_D] * w;      // exact: w in {0,1}
                v.y = Xs[(size_t)(n0 + 1) * DIM_D] * w;
                v.z = Xs[(size_t)(n0 + 2) * DIM_D] * w;
                v.w = Xs[(size_t)(n0 + 3) * DIM_D] * w;
                *reinterpret_cast<float4*>(&srow[n0 ^ pcs]) = v;
            }
        }
        __syncthreads();

        // ---------- register-tiled masked GEMM over this phase's 64 d ----------
        const float* pb0 = pbase + p * PH_ROWS;
        for (int db = 0; db < PH_ROWS; db += 4) {
            // b-fragments: 8 projection rows, 4 consecutive d each (L1/L2-hot)
            float4 b[8];
            #pragma unroll
            for (int j = 0; j < 8; ++j)
                b[j] = *reinterpret_cast<const float4*>(pb0 + db + (size_t)j * DIM_D);

            #pragma unroll
            for (int dd = 0; dd < 4; ++dd) {       // ascending d within block
                const int d2 = db + dd;            // phase-local row
                const int P  = C0 ^ (4 * (d2 & 7));
                const float* r = &Xt[d2 * DIM_N + P];
                const float4 q0 = *reinterpret_cast<const float4*>(r);        // n=C0..+3
                const float4 q1 = *reinterpret_cast<const float4*>(r + 64);   // n=64+C0..

                #pragma unroll
                for (int j = 0; j < 8; ++j) {
                    const float bv = (dd == 0) ? b[j].x : (dd == 1) ? b[j].y
                                   : (dd == 2) ? b[j].z : b[j].w;
                    acc[j][0] = fmaf(bv, q0.x, acc[j][0]);   // serial dep: order fixed
                    acc[j][1] = fmaf(bv, q0.y, acc[j][1]);
                    acc[j][2] = fmaf(bv, q0.z, acc[j][2]);
                    acc[j][3] = fmaf(bv, q0.w, acc[j][3]);
                    acc[j][4] = fmaf(bv, q1.x, acc[j][4]);
                    acc[j][5] = fmaf(bv, q1.y, acc[j][5]);
                    acc[j][6] = fmaf(bv, q1.z, acc[j][6]);
                    acc[j][7] = fmaf(bv, q1.w, acc[j][7]);
                }
            }
        }
        if (p == 0) __syncthreads();               // all reads done before re-stage
    }

    // ---------- sign-pack (bit j = s0+j > 0) and store as int32 ----------
    const size_t inl_total = (size_t)NB_HG * DIM_N * 32;   // 8388608
    #pragma unroll
    for (int i = 0; i < 8; ++i) {
        int byte = 0;
        #pragma unroll
        for (int j = 0; j < 8; ++j)
            if (acc[j][i] > 0.0f) byte |= (1 << j);
        const int n = (i < 4) ? (C0 + i) : (64 + C0 + (i - 4));
        size_t idx;
        if (type == 2)
            idx = inl_total + ((size_t)hg * DIM_N + n) * 16 + ts;
        else
            idx = ((size_t)hg * DIM_N + n) * 32 + (type == 1 ? 16 : 0) + ts;
        out[idx] = byte;
    }
}

extern "C" void kernel_launch(void* const* d_in, const int* in_sizes, int n_in,
                              void* d_out, int out_size, void* d_ws, size_t ws_size,
                              hipStream_t stream) {
    const float* data = (const float*)d_in[0];   // (1,32,64,128,128) fp32
    const float* mask = (const float*)d_in[1];   // (1,32,64,128) fp32, values {0,1}
    const float* proj = (const float*)d_in[2];   // (256,128) fp32
    int* out = (int*)d_out;                      // 8388608 inlier + 4194304 outlier int32

    dim3 grid(3, NB_HG);
    qjl_sketch_kernel<<<grid, 256, 0, stream>>>(data, mask, proj, out);
}

// Round 9
// 228.964 us; speedup vs baseline: 2.0299x; 1.6044x over previous
//
#include <hip/hip_runtime.h>

#define NB_HG 2048   // H*G = 32*64
#define DIM_N 128
#define DIM_D 128

// Numerics: golden = per-element strictly sequential ascending-d fp32 FMA
// (verified bit-exact rounds 4-8). Masked-out entries are exact zeros and
// contribute nothing to the chain (fmaf(b,±0,acc)==acc for all reachable acc;
// -0/+0 transitions can't affect the >0 test), so each output's chain is
// EQUIVALENT to the sequential chain over only its selected d's, ascending.
// This kernel compacts the selected d's per (hg,type) -> FMA work halves.
// LDS layout: Xt[ci][n ^ 4*(ci&7)] float4-XOR swizzle (conflict-free both
// ways, SQ_LDS_BANK_CONFLICT=0 verified rounds 5-8; row index is now ci).
__global__ __launch_bounds__(256)
void qjl_sketch_kernel(const float* __restrict__ data,
                       const float* __restrict__ mask,
                       const float* __restrict__ proj,
                       int* __restrict__ out)
{
    __shared__ float Xt[DIM_D * DIM_N];   // 64 KB (worst case K=128 rows)
    __shared__ int   cidx[DIM_D];
    __shared__ int   wcnt[2];

    const int type = blockIdx.x;   // 0: inlier s<128, 1: inlier s>=128, 2: outlier s<128
    const int hg   = blockIdx.y;
    const int tid  = threadIdx.x;

    // ---------- build compacted ascending list of selected d's ----------
    bool sel = false; int pos = 0, w = 0;
    if (tid < 128) {                               // waves 0,1 only (whole waves)
        const float m = mask[hg * DIM_D + tid];    // exactly 0.0f or 1.0f
        sel = (type == 2) ? (m != 0.0f) : (m == 0.0f);
        const unsigned long long bal = __ballot(sel);
        const int lane = tid & 63;
        w = tid >> 6;
        if (lane == 0) wcnt[w] = __popcll(bal);
        pos = __popcll(bal & ((1ull << lane) - 1ull));
    }
    __syncthreads();
    if (sel) cidx[pos + (w ? wcnt[0] : 0)] = tid;  // tid == d, order preserved
    __syncthreads();
    const int K = wcnt[0] + wcnt[1];               // selected-row count (uniform)

    // ---------- stage selected rows, transposed + swizzled (no multiply) ----------
    {
        const int ci = tid & 127;                  // compacted row this thread stages
        const int nh = tid >> 7;                   // 0,1: n-half (64 each)
        if (ci < K) {
            const int   dg = cidx[ci];
            const float* Xs = data + (size_t)hg * (DIM_N * DIM_D) + dg;
            const int   pcs = 4 * (ci & 7);
            float* row = &Xt[ci * DIM_N];
            #pragma unroll
            for (int g = 0; g < 16; ++g) {
                const int n0 = nh * 64 + g * 4;    // 4-aligned logical n block
                float4 v;
                v.x = Xs[(size_t)(n0 + 0) * DIM_D];
                v.y = Xs[(size_t)(n0 + 1) * DIM_D];
                v.z = Xs[(size_t)(n0 + 2) * DIM_D];
                v.w = Xs[(size_t)(n0 + 3) * DIM_D];
                *reinterpret_cast<float4*>(&row[n0 ^ pcs]) = v;
            }
        }
    }
    __syncthreads();

    // ---------- register-tiled GEMM over K compacted rows ----------
    const int tn = tid & 15;                       // 16 n-groups
    const int ts = tid >> 4;                       // 16 s-groups
    const int C0 = 4 * tn;
    const int s0 = ((type == 1) ? 128 : 0) + ts * 8;
    const float* pbase = proj + (size_t)s0 * DIM_D;

    float acc[8][8];                               // [j: s-bit][i: n-slot]
    #pragma unroll
    for (int j = 0; j < 8; ++j)
        #pragma unroll
        for (int i = 0; i < 8; ++i) acc[j][i] = 0.0f;

    #pragma unroll 2
    for (int ci = 0; ci < K; ++ci) {               // ascending selected d
        const int dg = cidx[ci];                   // uniform LDS read (broadcast)
        float b[8];
        #pragma unroll
        for (int j = 0; j < 8; ++j)
            b[j] = pbase[(size_t)j * DIM_D + dg];  // L1-hot, 16-thread shared

        const int P = C0 ^ (4 * (ci & 7));
        const float* r = &Xt[ci * DIM_N + P];
        const float4 q0 = *reinterpret_cast<const float4*>(r);        // n=C0..+3
        const float4 q1 = *reinterpret_cast<const float4*>(r + 64);   // n=64+C0..

        #pragma unroll
        for (int j = 0; j < 8; ++j) {
            const float bv = b[j];
            acc[j][0] = fmaf(bv, q0.x, acc[j][0]); // serial dep: order fixed
            acc[j][1] = fmaf(bv, q0.y, acc[j][1]);
            acc[j][2] = fmaf(bv, q0.z, acc[j][2]);
            acc[j][3] = fmaf(bv, q0.w, acc[j][3]);
            acc[j][4] = fmaf(bv, q1.x, acc[j][4]);
            acc[j][5] = fmaf(bv, q1.y, acc[j][5]);
            acc[j][6] = fmaf(bv, q1.z, acc[j][6]);
            acc[j][7] = fmaf(bv, q1.w, acc[j][7]);
        }
    }

    // ---------- sign-pack (bit j = s0+j > 0) and store as int32 ----------
    const size_t inl_total = (size_t)NB_HG * DIM_N * 32;   // 8388608
    #pragma unroll
    for (int i = 0; i < 8; ++i) {
        int byte = 0;
        #pragma unroll
        for (int j = 0; j < 8; ++j)
            if (acc[j][i] > 0.0f) byte |= (1 << j);
        const int n = (i < 4) ? (C0 + i) : (64 + C0 + (i - 4));
        size_t idx;
        if (type == 2)
            idx = inl_total + ((size_t)hg * DIM_N + n) * 16 + ts;
        else
            idx = ((size_t)hg * DIM_N + n) * 32 + (type == 1 ? 16 : 0) + ts;
        out[idx] = byte;
    }
}

extern "C" void kernel_launch(void* const* d_in, const int* in_sizes, int n_in,
                              void* d_out, int out_size, void* d_ws, size_t ws_size,
                              hipStream_t stream) {
    const float* data = (const float*)d_in[0];   // (1,32,64,128,128) fp32
    const float* mask = (const float*)d_in[1];   // (1,32,64,128) fp32, values {0,1}
    const float* proj = (const float*)d_in[2];   // (256,128) fp32
    int* out = (int*)d_out;                      // 8388608 inlier + 4194304 outlier int32

    dim3 grid(3, NB_HG);
    qjl_sketch_kernel<<<grid, 256, 0, stream>>>(data, mask, proj, out);
}

// Round 10
// 202.888 us; speedup vs baseline: 2.2908x; 1.1285x over previous
//
#include <hip/hip_runtime.h>

#define NB_HG 2048   // H*G = 32*64
#define DIM_N 128
#define DIM_D 128
#define DIM_S 256

// Numerics: golden = per-element strictly sequential ascending-d fp32 FMA over
// the SELECTED d's only (masked-out terms are exact zeros; fmaf(b,±0,acc)==acc).
// Verified bit-exact in rounds 4-9. Compaction + phase split preserve order.
// LDS: Xt[cl][n ^ 4*(cl&7)] float4-XOR swizzle — SQ_LDS_BANK_CONFLICT=0
// verified rounds 5-9. Two 64-row phases -> 32.5 KB LDS -> 4 blocks/CU.
// projT (d-major) in d_ws turns 8 scalar b-gathers/iter into 2 float4 loads.

__global__ void transpose_proj_kernel(const float* __restrict__ proj,
                                      float* __restrict__ projT)
{
    const int d = blockIdx.x;                      // 128
    const int s = threadIdx.x;                     // 256
    projT[d * DIM_S + s] = proj[s * DIM_D + d];    // coalesced write
}

template<bool TP>
__global__ __launch_bounds__(256)
void qjl_sketch_kernel(const float* __restrict__ data,
                       const float* __restrict__ mask,
                       const float* __restrict__ pmat,   // TP ? projT[d][s] : proj[s][d]
                       int* __restrict__ out)
{
    __shared__ float Xt[64 * DIM_N];               // 32 KB (one 64-row phase)
    __shared__ int   cidx[DIM_D];
    __shared__ int   wcnt[2];

    const int type = blockIdx.x;   // 0: inlier s<128, 1: inlier s>=128, 2: outlier s<128
    const int hg   = blockIdx.y;
    const int tid  = threadIdx.x;

    // ---------- build compacted ascending list of selected d's ----------
    bool sel = false; int pos = 0, w = 0;
    if (tid < 128) {                               // waves 0,1 only (whole waves)
        const float m = mask[hg * DIM_D + tid];    // exactly 0.0f or 1.0f
        sel = (type == 2) ? (m != 0.0f) : (m == 0.0f);
        const unsigned long long bal = __ballot(sel);
        const int lane = tid & 63;
        w = tid >> 6;
        if (lane == 0) wcnt[w] = __popcll(bal);
        pos = __popcll(bal & ((1ull << lane) - 1ull));
    }
    __syncthreads();
    if (sel) cidx[pos + (w ? wcnt[0] : 0)] = tid;  // tid == d, ascending preserved
    __syncthreads();
    const int K = wcnt[0] + wcnt[1];               // uniform across block

    const int tn = tid & 15;                       // 16 n-groups
    const int ts = tid >> 4;                       // 16 s-groups
    const int C0 = 4 * tn;
    const int s0 = ((type == 1) ? 128 : 0) + ts * 8;

    float acc[8][8];                               // [j: s-bit][i: n-slot]
    #pragma unroll
    for (int j = 0; j < 8; ++j)
        #pragma unroll
        for (int i = 0; i < 8; ++i) acc[j][i] = 0.0f;

    // staging thread mapping (constant across phases)
    const int cl_s = tid & 63;                     // local LDS row this thread stages
    const int nh   = tid >> 6;                     // 0..3: 32-wide n quarter
    const int pcs  = 4 * (cl_s & 7);
    float* srow = &Xt[cl_s * DIM_N];

    auto STAGE = [&](int base, int kp) {
        if (cl_s < kp) {
            const int dg = cidx[base + cl_s];
            const float* Xs = data + (size_t)hg * (DIM_N * DIM_D) + dg;
            #pragma unroll
            for (int g = 0; g < 8; ++g) {
                const int n0 = nh * 32 + g * 4;    // 4-aligned logical n block
                float4 v;
                v.x = Xs[(size_t)(n0 + 0) * DIM_D];
                v.y = Xs[(size_t)(n0 + 1) * DIM_D];
                v.z = Xs[(size_t)(n0 + 2) * DIM_D];
                v.w = Xs[(size_t)(n0 + 3) * DIM_D];
                *reinterpret_cast<float4*>(&srow[n0 ^ pcs]) = v;
            }
        }
    };

    auto COMPUTE = [&](int base, int kp) {
        #pragma unroll 2
        for (int cl = 0; cl < kp; ++cl) {          // ascending selected d
            const int dg = cidx[base + cl];        // uniform LDS broadcast
            float bv[8];
            if (TP) {
                const float* pr = pmat + (size_t)dg * DIM_S + s0;
                const float4 b0 = *reinterpret_cast<const float4*>(pr);
                const float4 b1 = *reinterpret_cast<const float4*>(pr + 4);
                bv[0]=b0.x; bv[1]=b0.y; bv[2]=b0.z; bv[3]=b0.w;
                bv[4]=b1.x; bv[5]=b1.y; bv[6]=b1.z; bv[7]=b1.w;
            } else {
                #pragma unroll
                for (int j = 0; j < 8; ++j)
                    bv[j] = pmat[(size_t)(s0 + j) * DIM_D + dg];
            }

            const int P = C0 ^ (4 * (cl & 7));
            const float* r = &Xt[cl * DIM_N + P];
            const float4 q0 = *reinterpret_cast<const float4*>(r);        // n=C0..+3
            const float4 q1 = *reinterpret_cast<const float4*>(r + 64);   // n=64+C0..

            #pragma unroll
            for (int j = 0; j < 8; ++j) {
                acc[j][0] = fmaf(bv[j], q0.x, acc[j][0]);   // serial dep: order fixed
                acc[j][1] = fmaf(bv[j], q0.y, acc[j][1]);
                acc[j][2] = fmaf(bv[j], q0.z, acc[j][2]);
                acc[j][3] = fmaf(bv[j], q0.w, acc[j][3]);
                acc[j][4] = fmaf(bv[j], q1.x, acc[j][4]);
                acc[j][5] = fmaf(bv[j], q1.y, acc[j][5]);
                acc[j][6] = fmaf(bv[j], q1.z, acc[j][6]);
                acc[j][7] = fmaf(bv[j], q1.w, acc[j][7]);
            }
        }
    };

    const int k0 = (K < 64) ? K : 64;
    STAGE(0, k0);
    __syncthreads();
    COMPUTE(0, k0);
    if (K > 64) {                                  // K uniform -> no barrier divergence
        __syncthreads();
        STAGE(64, K - 64);
        __syncthreads();
        COMPUTE(64, K - 64);
    }

    // ---------- sign-pack (bit j = s0+j > 0) and store as int32 ----------
    const size_t inl_total = (size_t)NB_HG * DIM_N * 32;   // 8388608
    #pragma unroll
    for (int i = 0; i < 8; ++i) {
        int byte = 0;
        #pragma unroll
        for (int j = 0; j < 8; ++j)
            if (acc[j][i] > 0.0f) byte |= (1 << j);
        const int n = (i < 4) ? (C0 + i) : (64 + C0 + (i - 4));
        size_t idx;
        if (type == 2)
            idx = inl_total + ((size_t)hg * DIM_N + n) * 16 + ts;
        else
            idx = ((size_t)hg * DIM_N + n) * 32 + (type == 1 ? 16 : 0) + ts;
        out[idx] = byte;
    }
}

extern "C" void kernel_launch(void* const* d_in, const int* in_sizes, int n_in,
                              void* d_out, int out_size, void* d_ws, size_t ws_size,
                              hipStream_t stream) {
    const float* data = (const float*)d_in[0];   // (1,32,64,128,128) fp32
    const float* mask = (const float*)d_in[1];   // (1,32,64,128) fp32, values {0,1}
    const float* proj = (const float*)d_in[2];   // (256,128) fp32
    int* out = (int*)d_out;                      // 8388608 inlier + 4194304 outlier int32

    dim3 grid(3, NB_HG);
    const size_t tp_bytes = (size_t)DIM_D * DIM_S * sizeof(float);   // 128 KB
    if (ws_size >= tp_bytes) {
        float* projT = (float*)d_ws;
        transpose_proj_kernel<<<DIM_D, DIM_S, 0, stream>>>(proj, projT);
        qjl_sketch_kernel<true><<<grid, 256, 0, stream>>>(data, mask, projT, out);
    } else {
        qjl_sketch_kernel<false><<<grid, 256, 0, stream>>>(data, mask, proj, out);
    }
}